// Round 8
// baseline (729.136 us; speedup 1.0000x reference)
//
#include <hip/hip_runtime.h>
#include <stdint.h>

#define HID 256
#define BATCH 16384
#define SEQ 20
#define OUTF 214
#define BM 64
#define NBLK (BATCH/BM)   // 256 blocks, one per CU
#define ROWE 264          // h row stride in bf16 elems

typedef __attribute__((ext_vector_type(8))) short short8;
typedef __attribute__((ext_vector_type(4))) float f32x4;
typedef __attribute__((ext_vector_type(2))) float f32x2;

#define MFMA(a,b,c) __builtin_amdgcn_mfma_f32_16x16x32_bf16((a),(b),(c),0,0,0)
// soft barrier: order LDS only; global loads/stores drain across the barrier
#define SBAR() asm volatile("s_waitcnt lgkmcnt(0)\n\ts_barrier" ::: "memory")
#define SCHEDF() __builtin_amdgcn_sched_barrier(0)   // scheduling fence: no cross-motion

__device__ __forceinline__ unsigned short f2bf(float f) {
    unsigned int u = __builtin_bit_cast(unsigned int, f);
    u += 0x7FFFu + ((u >> 16) & 1u);   // RNE
    return (unsigned short)(u >> 16);
}
__device__ __forceinline__ unsigned int cvtpk(float lo, float hi) {
    unsigned int r;
    asm("v_cvt_pk_bf16_f32 %0, %1, %2" : "=v"(r) : "v"(lo), "v"(hi));  // RNE, lo->[15:0]
    return r;
}
__device__ __forceinline__ float sigm(float x)     { return __fdividef(1.0f, 1.0f + __expf(-x)); }
__device__ __forceinline__ float tanhfast(float x) { return 1.0f - __fdividef(2.0f, __expf(2.0f*x) + 1.0f); }

// ---------------- prep: pack weights into MFMA fragment-linear layout ----------------
// frag layout for a [Ntiles][Ktiles] matrix of 16x32 tiles: element (n,k) lives at
// short index (((n>>4)*KT + (k>>5))*64 + ((n&15) | (((k>>3)&3)<<4)))*8 + (k&7)
__global__ __launch_bounds__(256) void prep_kernel(
    const float* __restrict__ W_proj, const float* __restrict__ W_ih,
    const float* __restrict__ W_hh,  const float* __restrict__ b_ih,
    const float* __restrict__ b_hh,  const float* __restrict__ W_tech,
    const float* __restrict__ b_tech, const float* __restrict__ W_phase,
    const float* __restrict__ b_phase, const float* __restrict__ W_time,
    const float* __restrict__ b_time,
    unsigned short* __restrict__ Wc, unsigned short* __restrict__ Wi,
    unsigned short* __restrict__ Wo, unsigned short* __restrict__ Wp,
    float* __restrict__ b_comb, float* __restrict__ b_out)
{
    const int n = blockIdx.x;    // 0..1023 (gate row)
    const int k = threadIdx.x;   // 0..255
    const int lane = (n & 15) | (((k >> 3) & 3) << 4);
    const int e  = k & 7;
    const int tn = n >> 4;
    {
        float wi = W_ih[n*HID + k], wh = W_hh[n*HID + k];
        int idx = ((tn*8 + (k>>5))*64 + lane)*8 + e;
        Wi[idx] = f2bf(wi);
        Wc[idx] = f2bf(wi + wh);
    }
    if (n < 224) {   // out projection: [tech(200) | phase(13) | time(1) | zero-pad]
        float v = 0.0f;
        if (n < 200)       v = W_tech[n*HID + k];
        else if (n < 213)  v = W_phase[(n-200)*HID + k];
        else if (n == 213) v = W_time[k];
        int idx = ((tn*8 + (k>>5))*64 + lane)*8 + e;
        Wo[idx] = f2bf(v);
    }
    if (n < 256 && k < 128) {  // W_proj padded K 100->128
        float v = (k < 100) ? W_proj[n*100 + k] : 0.0f;
        int idx = ((tn*4 + (k>>5))*64 + lane)*8 + e;
        Wp[idx] = f2bf(v);
    }
    if (n < 4) b_comb[n*256 + k] = b_ih[n*256 + k] + b_hh[n*256 + k];
    if (n == 4 && k < 224) {
        float v = 0.0f;
        if (k < 200)       v = b_tech[k];
        else if (k < 213)  v = b_phase[k-200];
        else if (k == 213) v = b_time[0];
        b_out[k] = v;
    }
}

// ---------------- main persistent LSTM kernel ----------------
// 256 blocks x 1024 threads (16 waves, 4/SIMD, hard 128-reg cap), 64 batch rows.
// Wave w owns hidden slice [16w, 16w+16) (all 4 gates): acc 64 AGPR.
// Register discipline: scalarized weight addressing (readfirstlane) + sched_barrier
// fences between phases so arch-VGPR peak stays <= 64 (no scratch spills).
__global__ __launch_bounds__(1024, 4) void lstm_kernel(
    const float* __restrict__ noise, const float* __restrict__ b_proj,
    const unsigned short* __restrict__ Wc, const unsigned short* __restrict__ Wi,
    const unsigned short* __restrict__ Wo_g, const unsigned short* __restrict__ Wp,
    const float* __restrict__ b_comb, const float* __restrict__ b_out,
    float* __restrict__ out)
{
    __shared__ __attribute__((aligned(16))) unsigned short hbuf[2][BM * ROWE]; // 2 x 33.0 KiB
    __shared__ __attribute__((aligned(16))) float out_lds[BM * OUTF];          // 53.5 KiB
    __shared__ __attribute__((aligned(16))) float bi_lds[1024];                // 4 KiB
    __shared__ __attribute__((aligned(16))) float bo_lds[224];                 // 896 B

    const int tid  = threadIdx.x;
    const int w    = __builtin_amdgcn_readfirstlane(tid) >> 6;  // wave id 0..15, SGPR
    const int lane = tid & 63;
    const int lr   = lane & 15;    // D col (= batch m within tile)
    const int lq   = lane >> 4;    // k-slot group; D row group
    const int blk  = blockIdx.x;

    { // stage noise -> hbuf[1] as bf16 (cols 0..99), zero-pad 100..127
        const float* nsrc = noise + (size_t)blk * BM * 100;
        for (int i = tid; i < BM*100; i += 1024) {
            int m = i / 100; int kk = i - m*100;
            hbuf[1][m*ROWE + kk] = f2bf(nsrc[i]);
        }
        for (int i = tid; i < BM*28; i += 1024) {
            int m = i / 28; int kk = i - m*28;
            hbuf[1][m*ROWE + 100 + kk] = 0;
        }
        bi_lds[tid] = b_comb[tid];
        if (tid < 224) bo_lds[tid] = b_out[tid];
    }

    f32x4 c_[4];   // cell state for this wave's 16-col slice
    #pragma unroll
    for (int mt = 0; mt < 4; ++mt) c_[mt] = f32x4{0.f,0.f,0.f,0.f};

    SBAR();   // noise + biases staged

    // ---- x0 = noise @ W_proj.T + b_proj  (reads hbuf[1], writes hbuf[0])
    {
        f32x4 acc[4];
        #pragma unroll
        for (int mt = 0; mt < 4; ++mt) acc[mt] = f32x4{0.f,0.f,0.f,0.f};
        #pragma unroll
        for (int kk = 0; kk < 4; ++kk) {
            short8 b[4];
            #pragma unroll
            for (int mt = 0; mt < 4; ++mt)
                b[mt] = *(const short8*)&hbuf[1][(mt*16+lr)*ROWE + kk*32 + lq*8];
            const int tb = __builtin_amdgcn_readfirstlane(w*4 + kk);
            short8 a = *(const short8*)&Wp[(tb*64 + lane)*8];
            #pragma unroll
            for (int mt = 0; mt < 4; ++mt)
                acc[mt] = MFMA(a, b[mt], acc[mt]);
        }
        f32x4 bp = *(const f32x4*)&b_proj[w*16 + lq*4];
        const int jb = w*16 + lq*4;
        #pragma unroll
        for (int mt = 0; mt < 4; ++mt) {
            f32x4 v = acc[mt] + bp;
            uint2 pk; pk.x = cvtpk(v.x, v.y); pk.y = cvtpk(v.z, v.w);
            *(uint2*)&hbuf[0][(mt*16+lr)*ROWE + jb] = pk;
        }
    }
    SBAR();   // x0 visible; p=0 -> hbuf[0] = s_0

    // gates+elementwise: wave's full slice in one pass (acc 64 AGPR)
    auto gepass = [&](const unsigned short* __restrict__ Wf, int pc) {
        f32x4 acc[4][4];
        #pragma unroll
        for (int g = 0; g < 4; ++g)
            #pragma unroll
            for (int mt = 0; mt < 4; ++mt) acc[g][mt] = f32x4{0.f,0.f,0.f,0.f};
        #pragma unroll
        for (int kk = 0; kk < 8; ++kk) {
            short8 b[4];
            #pragma unroll
            for (int mt = 0; mt < 4; ++mt)
                b[mt] = *(const short8*)&hbuf[pc][(mt*16+lr)*ROWE + kk*32 + lq*8];
            #pragma unroll
            for (int g = 0; g < 4; ++g) {
                const int tb = __builtin_amdgcn_readfirstlane((g*16 + w)*8 + kk);
                short8 a = *(const short8*)&Wf[(tb*64 + lane)*8];
                #pragma unroll
                for (int mt = 0; mt < 4; ++mt)
                    acc[g][mt] = MFMA(a, b[mt], acc[g][mt]);
            }
        }
        SCHEDF();   // MFMA pipeline regs die here; elementwise regs start fresh
        const int jb = w*16 + lq*4;
        f32x4 bi0 = *(const f32x4*)&bi_lds[0*256 + jb];
        f32x4 bi1 = *(const f32x4*)&bi_lds[1*256 + jb];
        f32x4 bi2 = *(const f32x4*)&bi_lds[2*256 + jb];
        f32x4 bi3 = *(const f32x4*)&bi_lds[3*256 + jb];
        #pragma unroll
        for (int mt = 0; mt < 4; ++mt) {
            f32x4 xi = acc[0][mt] + bi0;
            f32x4 xf = acc[1][mt] + bi1;
            f32x4 xg = acc[2][mt] + bi2;
            f32x4 xo = acc[3][mt] + bi3;
            f32x4 cc = c_[mt];
            float hh[4];
            #pragma unroll
            for (int r = 0; r < 4; ++r) {
                float iv = sigm(xi[r]);
                float fv = sigm(xf[r]);
                float gv = tanhfast(xg[r]);
                float ov = sigm(xo[r]);
                float cn = fv*cc[r] + iv*gv;
                cc[r] = cn;
                hh[r] = ov * tanhfast(cn);
            }
            c_[mt] = cc;
            uint2 pk; pk.x = cvtpk(hh[0], hh[1]); pk.y = cvtpk(hh[2], hh[3]);
            *(uint2*)&hbuf[pc^1][(mt*16+lr)*ROWE + jb] = pk;
        }
        SCHEDF();
    };

    // out-proj: h_new (hbuf[pc]) @ W_out.T + b_out -> out_lds; wave w -> col tile w
    auto oproj = [&](int pc) {
        if (w >= 14) return;   // waves 14,15 idle this phase
        f32x4 oa[4];
        #pragma unroll
        for (int mt = 0; mt < 4; ++mt) oa[mt] = f32x4{0.f,0.f,0.f,0.f};
        #pragma unroll
        for (int kk = 0; kk < 8; ++kk) {
            short8 b[4];
            #pragma unroll
            for (int mt = 0; mt < 4; ++mt)
                b[mt] = *(const short8*)&hbuf[pc][(mt*16+lr)*ROWE + kk*32 + lq*8];
            const int tb = __builtin_amdgcn_readfirstlane(w*8 + kk);
            short8 a = *(const short8*)&Wo_g[(tb*64 + lane)*8];
            #pragma unroll
            for (int mt = 0; mt < 4; ++mt) oa[mt] = MFMA(a, b[mt], oa[mt]);
        }
        SCHEDF();
        f32x4 bo = *(const f32x4*)&bo_lds[w*16 + lq*4];
        const int col = w*16 + lq*4;
        #pragma unroll
        for (int mt = 0; mt < 4; ++mt) {
            int row = mt*16 + lr;
            f32x4 v = oa[mt] + bo;
            if (w < 13) {
                f32x2 lo; lo.x = v.x; lo.y = v.y;
                f32x2 hi; hi.x = v.z; hi.y = v.w;
                *(f32x2*)&out_lds[row*OUTF + col]     = lo;   // 8B-aligned
                *(f32x2*)&out_lds[row*OUTF + col + 2] = hi;
            } else {   // tile 13: cols 208..213 valid, ReLU on 213
                if (lq == 0) {
                    f32x2 lo; lo.x = v.x; lo.y = v.y;
                    f32x2 hi; hi.x = v.z; hi.y = v.w;
                    *(f32x2*)&out_lds[row*OUTF + 208] = lo;
                    *(f32x2*)&out_lds[row*OUTF + 210] = hi;
                } else if (lq == 1) {
                    f32x2 lo; lo.x = v.x; lo.y = (v.y > 0.f) ? v.y : 0.f;  // col 213 = timing
                    *(f32x2*)&out_lds[row*OUTF + 212] = lo;
                }
            }
        }
    };

    // flat, fully-coalesced, non-temporal copy out_lds -> out (full 64B lines)
    auto copy_flat = [&](int t) {
        f32x4* dst = (f32x4*)(out + (size_t)t * BATCH * OUTF + (size_t)blk * BM * OUTF);
        const f32x4* src = (const f32x4*)out_lds;
        for (int it = 0; it < 4; ++it) {
            int i = tid + it*1024;
            if (i < BM*OUTF/4)   // 3424 f32x4
                __builtin_nontemporal_store(src[i], &dst[i]);
        }
        SCHEDF();   // copy's in-flight regs must not overlap gepass pipeline
    };

    int p = 0;
    for (int t = 0; t < SEQ; ++t) {
        if (t > 0) copy_flat(t-1);            // reads out_lds (written before last SBAR)
        gepass(t ? Wc : Wi, p);               // s_t -> s_{t+1} in hbuf[p^1]
        SBAR();                               // h_new visible; copy reads drained
        oproj(p^1);                           // out(t) = f(h_new) -> out_lds
        p ^= 1;
        SBAR();                               // out_lds(t) visible; oproj hbuf reads drained
    }
    copy_flat(SEQ-1);
}

extern "C" void kernel_launch(void* const* d_in, const int* in_sizes, int n_in,
                              void* d_out, int out_size, void* d_ws, size_t ws_size,
                              hipStream_t stream) {
    const float* noise   = (const float*)d_in[0];
    const float* W_proj  = (const float*)d_in[1];
    const float* b_proj  = (const float*)d_in[2];
    const float* W_ih    = (const float*)d_in[3];
    const float* W_hh    = (const float*)d_in[4];
    const float* b_ih    = (const float*)d_in[5];
    const float* b_hh    = (const float*)d_in[6];
    const float* W_tech  = (const float*)d_in[7];
    const float* b_tech  = (const float*)d_in[8];
    const float* W_phase = (const float*)d_in[9];
    const float* b_phase = (const float*)d_in[10];
    const float* W_time  = (const float*)d_in[11];
    const float* b_time  = (const float*)d_in[12];

    char* ws = (char*)d_ws;
    unsigned short* Wc = (unsigned short*)(ws);            // 512 KiB: frag(W_ih + W_hh)
    unsigned short* Wi = (unsigned short*)(ws + 524288);   // 512 KiB: frag(W_ih)
    unsigned short* Wo = (unsigned short*)(ws + 1048576);  // 112 KiB: frag(W_out padded to 224)
    unsigned short* Wp = (unsigned short*)(ws + 1163264);  //  64 KiB: frag(W_proj padded K=128)
    float* b_comb = (float*)(ws + 1228800);                //   4 KiB
    float* b_out  = (float*)(ws + 1232896);                // 896 B

    prep_kernel<<<1024, 256, 0, stream>>>(W_proj, W_ih, W_hh, b_ih, b_hh,
                                          W_tech, b_tech, W_phase, b_phase, W_time, b_time,
                                          Wc, Wi, Wo, Wp, b_comb, b_out);
    lstm_kernel<<<NBLK, 1024, 0, stream>>>(noise, b_proj, Wc, Wi, Wo, Wp, b_comb, b_out,
                                           (float*)d_out);
}

// Round 9
// 382.733 us; speedup vs baseline: 1.9051x; 1.9051x over previous
//
#include <hip/hip_runtime.h>
#include <stdint.h>

#define HID 256
#define BATCH 16384
#define SEQ 20
#define OUTF 214
#define BM 64
#define NBLK (BATCH/BM)   // 256 blocks, one per CU
#define ROWE 264          // h row stride in bf16 elems (rows 16B-aligned)

typedef __attribute__((ext_vector_type(8))) short short8;
typedef __attribute__((ext_vector_type(4))) float f32x4;
typedef __attribute__((ext_vector_type(2))) float f32x2;

#define MFMA(a,b,c) __builtin_amdgcn_mfma_f32_16x16x32_bf16((a),(b),(c),0,0,0)
// soft barrier: order LDS only; global loads/stores drain across the barrier
#define SBAR() asm volatile("s_waitcnt lgkmcnt(0)\n\ts_barrier" ::: "memory")

__device__ __forceinline__ unsigned short f2bf(float f) {
    unsigned int u = __builtin_bit_cast(unsigned int, f);
    u += 0x7FFFu + ((u >> 16) & 1u);   // RNE
    return (unsigned short)(u >> 16);
}
__device__ __forceinline__ unsigned int cvtpk(float lo, float hi) {
    unsigned int r;
    asm("v_cvt_pk_bf16_f32 %0, %1, %2" : "=v"(r) : "v"(lo), "v"(hi));  // RNE, lo->[15:0]
    return r;
}
__device__ __forceinline__ float sigm(float x)     { return __fdividef(1.0f, 1.0f + __expf(-x)); }
__device__ __forceinline__ float tanhfast(float x) { return 1.0f - __fdividef(2.0f, __expf(2.0f*x) + 1.0f); }

// ---------------- prep: pack weights into MFMA fragment-linear layout ----------------
// frag layout for a [Ntiles][Ktiles] matrix of 16x32 tiles: element (n,k) lives at
// short index (((n>>4)*KT + (k>>5))*64 + ((n&15) | (((k>>3)&3)<<4)))*8 + (k&7)
__global__ __launch_bounds__(256) void prep_kernel(
    const float* __restrict__ W_proj, const float* __restrict__ W_ih,
    const float* __restrict__ W_hh,  const float* __restrict__ b_ih,
    const float* __restrict__ b_hh,  const float* __restrict__ W_tech,
    const float* __restrict__ b_tech, const float* __restrict__ W_phase,
    const float* __restrict__ b_phase, const float* __restrict__ W_time,
    const float* __restrict__ b_time,
    unsigned short* __restrict__ Wc, unsigned short* __restrict__ Wi,
    unsigned short* __restrict__ Wo, unsigned short* __restrict__ Wp,
    float* __restrict__ b_comb, float* __restrict__ b_out)
{
    const int n = blockIdx.x;    // 0..1023 (gate row)
    const int k = threadIdx.x;   // 0..255
    const int lane = (n & 15) | (((k >> 3) & 3) << 4);
    const int e  = k & 7;
    const int tn = n >> 4;
    {
        float wi = W_ih[n*HID + k], wh = W_hh[n*HID + k];
        int idx = ((tn*8 + (k>>5))*64 + lane)*8 + e;
        Wi[idx] = f2bf(wi);
        Wc[idx] = f2bf(wi + wh);
    }
    if (n < 224) {   // out projection: [tech(200) | phase(13) | time(1) | zero-pad]
        float v = 0.0f;
        if (n < 200)       v = W_tech[n*HID + k];
        else if (n < 213)  v = W_phase[(n-200)*HID + k];
        else if (n == 213) v = W_time[k];
        int idx = ((tn*8 + (k>>5))*64 + lane)*8 + e;
        Wo[idx] = f2bf(v);
    }
    if (n < 256 && k < 128) {  // W_proj padded K 100->128
        float v = (k < 100) ? W_proj[n*100 + k] : 0.0f;
        int idx = ((tn*4 + (k>>5))*64 + lane)*8 + e;
        Wp[idx] = f2bf(v);
    }
    if (n < 4) b_comb[n*256 + k] = b_ih[n*256 + k] + b_hh[n*256 + k];
    if (n == 4 && k < 224) {
        float v = 0.0f;
        if (k < 200)       v = b_tech[k];
        else if (k < 213)  v = b_phase[k-200];
        else if (k == 213) v = b_time[0];
        b_out[k] = v;
    }
}

// ---------------- main persistent LSTM kernel ----------------
// 256 blocks x 512 threads (8 waves, 2/SIMD, 256-reg budget -> no spills).
// Per step: [copy_out(t-2)] SBAR [passA: gates half0 + elemwise]
//           [passB: gates half1 + out-tiles (shared b loads) + elemwise + out epilogue] SBAR
// Merging oproj into passB removes R4's mid-compute barrier and 32 ds_reads/wave/step.
__global__ __launch_bounds__(512, 2) void lstm_kernel(
    const float* __restrict__ noise, const float* __restrict__ b_proj,
    const unsigned short* __restrict__ Wc, const unsigned short* __restrict__ Wi,
    const unsigned short* __restrict__ Wo_g, const unsigned short* __restrict__ Wp,
    const float* __restrict__ b_comb, const float* __restrict__ b_out,
    float* __restrict__ out)
{
    __shared__ __attribute__((aligned(16))) unsigned short hbuf[2][BM * ROWE]; // 2 x 33.0 KiB
    __shared__ __attribute__((aligned(16))) float out_lds[BM * OUTF];          // 53.5 KiB
    __shared__ __attribute__((aligned(16))) float bi_lds[1024];                // 4 KiB
    __shared__ __attribute__((aligned(16))) float bo_lds[224];                 // 896 B

    const int tid  = threadIdx.x;
    const int w    = tid >> 6;     // wave id 0..7
    const int lane = tid & 63;
    const int lr   = lane & 15;    // D col (= batch m within tile)
    const int lq   = lane >> 4;    // k-slot group; D row group
    const int blk  = blockIdx.x;

    { // stage noise -> hbuf[1] as bf16 (cols 0..99), zero-pad 100..127; biases -> LDS
        const float* nsrc = noise + (size_t)blk * BM * 100;
        for (int i = tid; i < BM*100; i += 512) {
            int m = i / 100; int kk = i - m*100;
            hbuf[1][m*ROWE + kk] = f2bf(nsrc[i]);
        }
        for (int i = tid; i < BM*28; i += 512) {
            int m = i / 28; int kk = i - m*28;
            hbuf[1][m*ROWE + 100 + kk] = 0;
        }
        bi_lds[tid] = b_comb[tid];
        bi_lds[tid + 512] = b_comb[tid + 512];
        if (tid < 224) bo_lds[tid] = b_out[tid];
    }

    f32x4 c_[2][4];   // cell state per half
    #pragma unroll
    for (int P = 0; P < 2; ++P)
        #pragma unroll
        for (int mt = 0; mt < 4; ++mt) c_[P][mt] = f32x4{0.f,0.f,0.f,0.f};

    SBAR();   // noise + biases staged

    // ---- x0 = noise @ W_proj.T + b_proj  (reads hbuf[1], writes hbuf[0])
    {
        f32x4 acc[2][4];
        #pragma unroll
        for (int jt = 0; jt < 2; ++jt)
            #pragma unroll
            for (int mt = 0; mt < 4; ++mt) acc[jt][mt] = f32x4{0.f,0.f,0.f,0.f};
        #pragma unroll
        for (int kk = 0; kk < 4; ++kk) {
            short8 b[4];
            #pragma unroll
            for (int mt = 0; mt < 4; ++mt)
                b[mt] = *(const short8*)&hbuf[1][(mt*16+lr)*ROWE + kk*32 + lq*8];
            #pragma unroll
            for (int jt = 0; jt < 2; ++jt) {
                short8 a = *(const short8*)&Wp[(((w*2+jt)*4 + kk)*64 + lane)*8];
                #pragma unroll
                for (int mt = 0; mt < 4; ++mt)
                    acc[jt][mt] = MFMA(a, b[mt], acc[jt][mt]);
            }
        }
        #pragma unroll
        for (int jt = 0; jt < 2; ++jt) {
            const int jb = w*32 + jt*16 + lq*4;
            f32x4 bp = *(const f32x4*)&b_proj[jb];
            #pragma unroll
            for (int mt = 0; mt < 4; ++mt) {
                f32x4 v = acc[jt][mt] + bp;
                uint2 pk; pk.x = cvtpk(v.x, v.y); pk.y = cvtpk(v.z, v.w);
                *(uint2*)&hbuf[0][(mt*16+lr)*ROWE + jb] = pk;
            }
        }
    }
    // p=0 -> hbuf[0] = s_0; first loop-iter SBAR makes it visible

    // elementwise helper for half P from acc -> hbuf[pc^1]
    auto elemwise = [&](int P, f32x4 (&acc)[4][4], int pc) {
        const int jb = P*128 + w*16 + lq*4;
        f32x4 bi0 = *(const f32x4*)&bi_lds[0*256 + jb];
        f32x4 bi1 = *(const f32x4*)&bi_lds[1*256 + jb];
        f32x4 bi2 = *(const f32x4*)&bi_lds[2*256 + jb];
        f32x4 bi3 = *(const f32x4*)&bi_lds[3*256 + jb];
        #pragma unroll
        for (int mt = 0; mt < 4; ++mt) {
            f32x4 xi = acc[0][mt] + bi0;
            f32x4 xf = acc[1][mt] + bi1;
            f32x4 xg = acc[2][mt] + bi2;
            f32x4 xo = acc[3][mt] + bi3;
            f32x4 cc = c_[P][mt];
            float hh[4];
            #pragma unroll
            for (int r = 0; r < 4; ++r) {
                float iv = sigm(xi[r]);
                float fv = sigm(xf[r]);
                float gv = tanhfast(xg[r]);
                float ov = sigm(xo[r]);
                float cn = fv*cc[r] + iv*gv;
                cc[r] = cn;
                hh[r] = ov * tanhfast(cn);
            }
            c_[P][mt] = cc;
            uint2 pk; pk.x = cvtpk(hh[0], hh[1]); pk.y = cvtpk(hh[2], hh[3]);
            *(uint2*)&hbuf[pc^1][(mt*16+lr)*ROWE + jb] = pk;
        }
    };

    // passA: gates half 0
    auto passA = [&](const unsigned short* __restrict__ Wf, int pc) {
        f32x4 acc[4][4];
        #pragma unroll
        for (int g = 0; g < 4; ++g)
            #pragma unroll
            for (int mt = 0; mt < 4; ++mt) acc[g][mt] = f32x4{0.f,0.f,0.f,0.f};
        #pragma unroll
        for (int kk = 0; kk < 8; ++kk) {
            short8 b[4];
            #pragma unroll
            for (int mt = 0; mt < 4; ++mt)
                b[mt] = *(const short8*)&hbuf[pc][(mt*16+lr)*ROWE + kk*32 + lq*8];
            #pragma unroll
            for (int g = 0; g < 4; ++g) {
                short8 a = *(const short8*)&Wf[(((g*16 + w)*8 + kk)*64 + lane)*8];
                #pragma unroll
                for (int mt = 0; mt < 4; ++mt)
                    acc[g][mt] = MFMA(a, b[mt], acc[g][mt]);
            }
        }
        elemwise(0, acc, pc);
    };

    // passB: gates half 1 + out tiles (b loads shared); out epilogue if dowrite
    auto passB = [&](const unsigned short* __restrict__ Wf, int pc, bool dowrite) {
        f32x4 acc[4][4];
        f32x4 oa0[4], oa1[4];
        #pragma unroll
        for (int g = 0; g < 4; ++g)
            #pragma unroll
            for (int mt = 0; mt < 4; ++mt) acc[g][mt] = f32x4{0.f,0.f,0.f,0.f};
        #pragma unroll
        for (int mt = 0; mt < 4; ++mt) { oa0[mt] = f32x4{0.f,0.f,0.f,0.f}; oa1[mt] = f32x4{0.f,0.f,0.f,0.f}; }
        #pragma unroll
        for (int kk = 0; kk < 8; ++kk) {
            short8 b[4];
            #pragma unroll
            for (int mt = 0; mt < 4; ++mt)
                b[mt] = *(const short8*)&hbuf[pc][(mt*16+lr)*ROWE + kk*32 + lq*8];
            #pragma unroll
            for (int g = 0; g < 4; ++g) {
                short8 a = *(const short8*)&Wf[(((g*16 + 8 + w)*8 + kk)*64 + lane)*8];
                #pragma unroll
                for (int mt = 0; mt < 4; ++mt)
                    acc[g][mt] = MFMA(a, b[mt], acc[g][mt]);
            }
            {
                short8 a0 = *(const short8*)&Wo_g[((w*8 + kk)*64 + lane)*8];
                #pragma unroll
                for (int mt = 0; mt < 4; ++mt) oa0[mt] = MFMA(a0, b[mt], oa0[mt]);
            }
            if (w < 6) {
                short8 a1 = *(const short8*)&Wo_g[(((8+w)*8 + kk)*64 + lane)*8];
                #pragma unroll
                for (int mt = 0; mt < 4; ++mt) oa1[mt] = MFMA(a1, b[mt], oa1[mt]);
            }
        }
        elemwise(1, acc, pc);
        if (dowrite) {
            f32x4 bo0 = *(const f32x4*)&bo_lds[w*16 + lq*4];
            const int col0 = w*16 + lq*4;
            #pragma unroll
            for (int mt = 0; mt < 4; ++mt) {
                int row = mt*16 + lr;
                f32x4 v = oa0[mt] + bo0;
                f32x2 lo; lo.x = v.x; lo.y = v.y;
                f32x2 hi; hi.x = v.z; hi.y = v.w;
                *(f32x2*)&out_lds[row*OUTF + col0]     = lo;   // rows 856B -> 8B aligned
                *(f32x2*)&out_lds[row*OUTF + col0 + 2] = hi;
            }
            if (w < 5) {
                f32x4 bo1 = *(const f32x4*)&bo_lds[(8+w)*16 + lq*4];
                const int col1 = 128 + w*16 + lq*4;
                #pragma unroll
                for (int mt = 0; mt < 4; ++mt) {
                    int row = mt*16 + lr;
                    f32x4 v = oa1[mt] + bo1;
                    f32x2 lo; lo.x = v.x; lo.y = v.y;
                    f32x2 hi; hi.x = v.z; hi.y = v.w;
                    *(f32x2*)&out_lds[row*OUTF + col1]     = lo;
                    *(f32x2*)&out_lds[row*OUTF + col1 + 2] = hi;
                }
            } else if (w == 5) {   // tile 13: cols 208..213 valid, ReLU on 213
                f32x4 bo1 = *(const f32x4*)&bo_lds[13*16 + lq*4];
                #pragma unroll
                for (int mt = 0; mt < 4; ++mt) {
                    int row = mt*16 + lr;
                    f32x4 v = oa1[mt] + bo1;
                    if (lq == 0) {
                        f32x2 lo; lo.x = v.x; lo.y = v.y;
                        f32x2 hi; hi.x = v.z; hi.y = v.w;
                        *(f32x2*)&out_lds[row*OUTF + 208] = lo;
                        *(f32x2*)&out_lds[row*OUTF + 210] = hi;
                    } else if (lq == 1) {
                        f32x2 lo; lo.x = v.x; lo.y = (v.y > 0.f) ? v.y : 0.f;  // col 213 = timing
                        *(f32x2*)&out_lds[row*OUTF + 212] = lo;
                    }
                }
            }
        }
    };

    // out-proj only (final step): h (hbuf[pc]) @ W_out.T -> out_lds
    auto oproj_only = [&](int pc) {
        f32x4 oa0[4], oa1[4];
        #pragma unroll
        for (int mt = 0; mt < 4; ++mt) { oa0[mt] = f32x4{0.f,0.f,0.f,0.f}; oa1[mt] = f32x4{0.f,0.f,0.f,0.f}; }
        #pragma unroll
        for (int kk = 0; kk < 8; ++kk) {
            short8 b[4];
            #pragma unroll
            for (int mt = 0; mt < 4; ++mt)
                b[mt] = *(const short8*)&hbuf[pc][(mt*16+lr)*ROWE + kk*32 + lq*8];
            short8 a0 = *(const short8*)&Wo_g[((w*8 + kk)*64 + lane)*8];
            #pragma unroll
            for (int mt = 0; mt < 4; ++mt) oa0[mt] = MFMA(a0, b[mt], oa0[mt]);
            if (w < 6) {
                short8 a1 = *(const short8*)&Wo_g[(((8+w)*8 + kk)*64 + lane)*8];
                #pragma unroll
                for (int mt = 0; mt < 4; ++mt) oa1[mt] = MFMA(a1, b[mt], oa1[mt]);
            }
        }
        f32x4 bo0 = *(const f32x4*)&bo_lds[w*16 + lq*4];
        const int col0 = w*16 + lq*4;
        #pragma unroll
        for (int mt = 0; mt < 4; ++mt) {
            int row = mt*16 + lr;
            f32x4 v = oa0[mt] + bo0;
            f32x2 lo; lo.x = v.x; lo.y = v.y;
            f32x2 hi; hi.x = v.z; hi.y = v.w;
            *(f32x2*)&out_lds[row*OUTF + col0]     = lo;
            *(f32x2*)&out_lds[row*OUTF + col0 + 2] = hi;
        }
        if (w < 5) {
            f32x4 bo1 = *(const f32x4*)&bo_lds[(8+w)*16 + lq*4];
            const int col1 = 128 + w*16 + lq*4;
            #pragma unroll
            for (int mt = 0; mt < 4; ++mt) {
                int row = mt*16 + lr;
                f32x4 v = oa1[mt] + bo1;
                f32x2 lo; lo.x = v.x; lo.y = v.y;
                f32x2 hi; hi.x = v.z; hi.y = v.w;
                *(f32x2*)&out_lds[row*OUTF + col1]     = lo;
                *(f32x2*)&out_lds[row*OUTF + col1 + 2] = hi;
            }
        } else if (w == 5) {
            f32x4 bo1 = *(const f32x4*)&bo_lds[13*16 + lq*4];
            #pragma unroll
            for (int mt = 0; mt < 4; ++mt) {
                int row = mt*16 + lr;
                f32x4 v = oa1[mt] + bo1;
                if (lq == 0) {
                    f32x2 lo; lo.x = v.x; lo.y = v.y;
                    f32x2 hi; hi.x = v.z; hi.y = v.w;
                    *(f32x2*)&out_lds[row*OUTF + 208] = lo;
                    *(f32x2*)&out_lds[row*OUTF + 210] = hi;
                } else if (lq == 1) {
                    f32x2 lo; lo.x = v.x; lo.y = (v.y > 0.f) ? v.y : 0.f;
                    *(f32x2*)&out_lds[row*OUTF + 212] = lo;
                }
            }
        }
    };

    // flat, fully-coalesced, non-temporal copy out_lds -> out (full 64B lines)
    auto copy_flat = [&](int t) {
        f32x4* dst = (f32x4*)(out + (size_t)t * BATCH * OUTF + (size_t)blk * BM * OUTF);
        const f32x4* src = (const f32x4*)out_lds;
        for (int i = tid; i < BM*OUTF/4; i += 512)   // 3424 f32x4
            __builtin_nontemporal_store(src[i], &dst[i]);
    };

    int p = 0;
    for (int t = 0; t < SEQ; ++t) {
        if (t >= 2) copy_flat(t-2);           // out(t-2), written 2 barriers ago
        SBAR();   // copy reads done before this iter's out writes; h_t (hbuf[p]) visible
        const unsigned short* Wf = t ? Wc : Wi;
        passA(Wf, p);                         // gates[0:512] of h_{t+1}; elemwise -> hbuf[p^1]
        passB(Wf, p, t > 0);                  // gates[512:1024] + out(t-1) -> out_lds
        p ^= 1;
        SBAR();   // h_{t+1} + out_lds(t-1) visible
    }
    copy_flat(SEQ-2);   // out(18)
    SBAR();
    oproj_only(p);      // out(19) from h_20
    SBAR();
    copy_flat(SEQ-1);
}

extern "C" void kernel_launch(void* const* d_in, const int* in_sizes, int n_in,
                              void* d_out, int out_size, void* d_ws, size_t ws_size,
                              hipStream_t stream) {
    const float* noise   = (const float*)d_in[0];
    const float* W_proj  = (const float*)d_in[1];
    const float* b_proj  = (const float*)d_in[2];
    const float* W_ih    = (const float*)d_in[3];
    const float* W_hh    = (const float*)d_in[4];
    const float* b_ih    = (const float*)d_in[5];
    const float* b_hh    = (const float*)d_in[6];
    const float* W_tech  = (const float*)d_in[7];
    const float* b_tech  = (const float*)d_in[8];
    const float* W_phase = (const float*)d_in[9];
    const float* b_phase = (const float*)d_in[10];
    const float* W_time  = (const float*)d_in[11];
    const float* b_time  = (const float*)d_in[12];

    char* ws = (char*)d_ws;
    unsigned short* Wc = (unsigned short*)(ws);            // 512 KiB: frag(W_ih + W_hh)
    unsigned short* Wi = (unsigned short*)(ws + 524288);   // 512 KiB: frag(W_ih)
    unsigned short* Wo = (unsigned short*)(ws + 1048576);  // 112 KiB: frag(W_out padded to 224)
    unsigned short* Wp = (unsigned short*)(ws + 1163264);  //  64 KiB: frag(W_proj padded K=128)
    float* b_comb = (float*)(ws + 1228800);                //   4 KiB
    float* b_out  = (float*)(ws + 1232896);                // 896 B

    prep_kernel<<<1024, 256, 0, stream>>>(W_proj, W_ih, W_hh, b_ih, b_hh,
                                          W_tech, b_tech, W_phase, b_phase, W_time, b_time,
                                          Wc, Wi, Wo, Wp, b_comb, b_out);
    lstm_kernel<<<NBLK, 512, 0, stream>>>(noise, b_proj, Wc, Wi, Wo, Wp, b_comb, b_out,
                                          (float*)d_out);
}